// Round 15
// baseline (524.464 us; speedup 1.0000x reference)
//
#include <hip/hip_runtime.h>
#include <hip/hip_bf16.h>

#define HID 101
#define BATCH 1024
#define RPB 4
#define NBLK 256
#define NTHR 1024
#define TSEQ 256

#define A1SZ  (7*4*4*512)    // 57344 halfs
#define A2SZ  (7*4*7*512)    // 100352 halfs
#define A2OFF A1SZ
#define AOOFF (A1SZ + A2SZ)  // 157696
#define AOSZ  (4*512)

typedef _Float16 h8 __attribute__((ext_vector_type(8)));
typedef float f4 __attribute__((ext_vector_type(4)));

// ---------------------------------------------------------------------------
// Combined state vector (K=224, 7 k-tiles of 32):
//   k 0..100 : h1    k 101..103 : x    k 104 : one    k 112..212 : h2
// A1 (L1, kt0..3): k<101->W_hh1[g][k]; 101..103->W_ih1; 104->b1; else 0.
// A2 (L2, kt0..6): k<101->W_ih2[g][k]; 104->b2; 112..212->W_hh2[g][k-112]; else 0.
// AO (out head, frags for kt3..6): row j<3: k 112..212 -> Wl[j][k-112]; else 0.
// Fragment: lane l holds A[row=l&15][k = kt*32 + ((l>>4)&3)*8 + i], i=0..7.
// ---------------------------------------------------------------------------
__global__ void prep_kernel(const float* __restrict__ W_ih1, const float* __restrict__ W_hh1,
                            const float* __restrict__ b_ih1, const float* __restrict__ b_hh1,
                            const float* __restrict__ W_ih2, const float* __restrict__ W_hh2,
                            const float* __restrict__ b_ih2, const float* __restrict__ b_hh2,
                            const float* __restrict__ Wl, _Float16* __restrict__ wsA) {
    int idx = blockIdx.x * blockDim.x + threadIdx.x;
    int stride = gridDim.x * blockDim.x;
    for (int t = idx; t < A1SZ; t += stride) {
        int i = t & 7, lane = (t >> 3) & 63, kt = (t >> 9) & 3, tau = (t >> 11) & 3, w = t >> 13;
        int k = kt * 32 + ((lane >> 4) & 3) * 8 + i;
        int u = 16 * w + (lane & 15);
        float v = 0.f;
        if (u < HID) {
            int g = tau * HID + u;
            if (k < HID) v = W_hh1[g * HID + k];
            else if (k >= 101 && k <= 103) v = W_ih1[g * 3 + (k - 101)];
            else if (k == 104) v = b_ih1[g] + b_hh1[g];
        }
        wsA[t] = (_Float16)v;
    }
    for (int t = idx; t < A2SZ; t += stride) {
        int i = t & 7, lane = (t >> 3) & 63;
        int rem = t >> 9;
        int kt = rem % 7; rem /= 7;
        int tau = rem & 3, w = rem >> 2;
        int k = kt * 32 + ((lane >> 4) & 3) * 8 + i;
        int u = 16 * w + (lane & 15);
        float v = 0.f;
        if (u < HID) {
            int g = tau * HID + u;
            if (k < HID) v = W_ih2[g * HID + k];
            else if (k == 104) v = b_ih2[g] + b_hh2[g];
            else if (k >= 112 && k < 213) v = W_hh2[g * HID + (k - 112)];
        }
        wsA[A2OFF + t] = (_Float16)v;
    }
    for (int t = idx; t < AOSZ; t += stride) {
        int i = t & 7, lane = (t >> 3) & 63, kk = (t >> 9) & 3;
        int k = (kk + 3) * 32 + ((lane >> 4) & 3) * 8 + i;
        int j = lane & 15;
        float v = (j < 3 && k >= 112 && k < 213) ? Wl[j * HID + (k - 112)] : 0.f;
        wsA[AOOFF + t] = (_Float16)v;
    }
}

__device__ __forceinline__ float sigm(float z) {
    return __builtin_amdgcn_rcpf(1.f + __expf(-z));
}
__device__ __forceinline__ float tanhf_(float z) {
    return 1.f - 2.f * __builtin_amdgcn_rcpf(__expf(2.f * z) + 1.f);
}

#define MFMA(acc, a, b) acc = __builtin_amdgcn_mfma_f32_16x16x32_f16(a, b, acc, 0, 0, 0)

// ---------------------------------------------------------------------------
// persistent kernel: 256 blocks x 1024 thr (16 waves, 4 waves/SIMD).
// Tau-split for occupancy: wave w (0..6) holds tau{0,1} of unit-group w;
// wave w+8 (8..14) holds tau{2,3}. 88 weight VGPRs/wave -> fits 128-reg
// budget at 4 waves/SIMD (2x the old occupancy).
// Teacher stage (2 barriers):
//   ph1: all mfma-waves: A(t) + B(t-1) partial-tau MFMAs -> zwA/zwB;
//        wave7: out(t-2) MFMA.
//   ph2: waves0-6: ew-L1 -> h1 -> Wt; waves8-14: ew-L2 -> h2 -> Wt;
//        wave7: store out, stage x(t+1).
// Future: 5-barrier serial steps. Dataflow identical to the verified r9 graph.
// ---------------------------------------------------------------------------
__global__ __launch_bounds__(NTHR) void lstm_kernel(
    const float* __restrict__ input, const _Float16* __restrict__ wsA,
    const float* __restrict__ bl, int steps, float* __restrict__ out)
{
    const int tid = threadIdx.x;
    const int wid = tid >> 6, lane = tid & 63;
    const int q = lane >> 4, col = lane & 15;
    const int r0 = blockIdx.x * RPB;
    const int ostride = steps * 3;

    const int w = wid & 7;                       // unit-group (0..6 valid)
    const bool mfmaw = (w < 7) && (wid != 7);    // waves 0-6, 8-14
    const int tb = (wid < 8) ? 0 : 2;            // tau base for this wave

    __shared__ _Float16 Sb[2][3584];       // combined state buffers
    __shared__ float zwA[7][4][4][16];     // L1 z exchange [w][tau][row][unit]
    __shared__ float zwB[7][4][4][16];     // L2 z exchange
    __shared__ _Float16 xpre[TSEQ * 12];   // staged inputs (f16)

    // --- weights: volatile loads -> execute once, stay register-resident ---
    h8 A1[2][4];   // tau tb, tb+1
    h8 A2[2][7];
    h8 AO[4];      // wave 7 only: out head
    if (mfmaw) {
        #pragma unroll
        for (int tt = 0; tt < 2; tt++) {
            #pragma unroll
            for (int kt = 0; kt < 4; kt++)
                A1[tt][kt] = *(const volatile h8*)(
                    wsA + ((size_t)((w * 4 + tb + tt) * 4 + kt) * 512 + lane * 8));
            #pragma unroll
            for (int kt = 0; kt < 7; kt++)
                A2[tt][kt] = *(const volatile h8*)(
                    wsA + (size_t)A2OFF + ((size_t)((w * 4 + tb + tt) * 7 + kt) * 512 + lane * 8));
        }
    } else if (wid == 7) {
        #pragma unroll
        for (int kt = 0; kt < 4; kt++)
            AO[kt] = *(const volatile h8*)(
                wsA + (size_t)AOOFF + ((size_t)(kt) * 512 + lane * 8));
    }
    const float bl0 = bl[0], bl1 = bl[1], bl2 = bl[2];

    // lane geometry
    const int r_ew = lane & 3, ul = lane >> 2;
    const int uw = (wid < 8) ? wid : (wid - 8);          // ew unit-group
    const int u = 16 * uw + ul;
    const bool ewv = (uw < 7) && (u < HID);
    const int slot1 = (u >> 3) * 128 + r_ew * 8 + (u & 7);           // h1 (k=u)
    const int slot2 = (14 + (u >> 3)) * 128 + r_ew * 8 + (u & 7);    // h2 (k=112+u)
    const int boff = q * 128 + col * 8;
    const int xr = lane / 3, xj = lane - 3 * xr;                     // wave7 lanes<12
    const int xoff = 12 * 128 + xr * 8 + 5 + xj;                     // x slot (k=101+xj)

    // ---- prologue ----
    for (int i2 = tid; i2 < 3584; i2 += NTHR) {
        Sb[0][i2] = (_Float16)0.f; Sb[1][i2] = (_Float16)0.f;
    }
    for (int g = tid; g < RPB * TSEQ * 3; g += NTHR) {
        int r = g / (TSEQ * 3), rem = g - r * (TSEQ * 3);
        int tt = rem / 3, j = rem - 3 * tt;
        xpre[tt * 12 + r * 3 + j] = (_Float16)input[(size_t)(r0 + r) * (TSEQ * 3) + rem];
    }
    __syncthreads();
    if (tid < 16) {   // bias-one slot k=104, both buffers
        Sb[0][13 * 128 + tid * 8] = (_Float16)1.0f;
        Sb[1][13 * 128 + tid * 8] = (_Float16)1.0f;
    }
    if (tid < 12) {  // x(0) -> S[0]
        int r = tid / 3, j = tid - 3 * (tid / 3);
        Sb[0][12 * 128 + r * 8 + 5 + j] = xpre[r * 3 + j];
    }
    float c1 = 0.f, c2 = 0.f;   // c1 live in waves 0-6; c2 in waves 8-14
    __syncthreads();

    // ---- teacher-forced pipeline: 2 barriers per step ----
    for (int t = 0; t < TSEQ; ++t) {
        _Float16* Rb = Sb[t & 1];
        _Float16* Wt = Sb[1 - (t & 1)];
        f4 ao = {0.f, 0.f, 0.f, 0.f};
        // ---- phase 1: MFMAs ----
        if (mfmaw) {
            f4 a0 = {0.f,0.f,0.f,0.f}, a1 = a0, b0 = a0, b1 = a0;
            #pragma unroll
            for (int kt = 0; kt < 7; kt++) {
                h8 bf = (_Float16)0.f;
                if (col < 4) bf = *(const h8*)(Rb + kt * 512 + boff);
                if (kt < 4) { MFMA(a0, A1[0][kt], bf); MFMA(a1, A1[1][kt], bf); }
                if (t >= 1) { MFMA(b0, A2[0][kt], bf); MFMA(b1, A2[1][kt], bf); }
            }
            if (col < 4) {
                *(f4*)&zwA[w][tb + 0][col][4 * q] = a0;
                *(f4*)&zwA[w][tb + 1][col][4 * q] = a1;
                if (t >= 1) {
                    *(f4*)&zwB[w][tb + 0][col][4 * q] = b0;
                    *(f4*)&zwB[w][tb + 1][col][4 * q] = b1;
                }
            }
        } else if (wid == 7 && t >= 2) {
            #pragma unroll
            for (int kk = 0; kk < 4; kk++) {
                h8 bf = (_Float16)0.f;
                if (col < 4) bf = *(const h8*)(Rb + (kk + 3) * 512 + boff);
                MFMA(ao, AO[kk], bf);
            }
        }
        __syncthreads();
        // ---- phase 2: elementwise + stores ----
        if (wid < 7) {          // L1 ew
            float z0 = zwA[wid][0][r_ew][ul], z1 = zwA[wid][1][r_ew][ul];
            float z2 = zwA[wid][2][r_ew][ul], z3 = zwA[wid][3][r_ew][ul];
            float ig = sigm(z0), fg = sigm(z1), gg = tanhf_(z2), og = sigm(z3);
            c1 = fg * c1 + ig * gg;
            float h1v = og * tanhf_(c1);
            if (ewv) Wt[slot1] = (_Float16)h1v;
        } else if (wid >= 8 && wid < 15) {   // L2 ew
            if (t >= 1) {
                int w2 = wid - 8;
                float z0 = zwB[w2][0][r_ew][ul], z1 = zwB[w2][1][r_ew][ul];
                float z2 = zwB[w2][2][r_ew][ul], z3 = zwB[w2][3][r_ew][ul];
                float ig = sigm(z0), fg = sigm(z1), gg = tanhf_(z2), og = sigm(z3);
                c2 = fg * c2 + ig * gg;
                float h2v = og * tanhf_(c2);
                if (ewv) Wt[slot2] = (_Float16)h2v;
            }
        } else if (wid == 7) {
            if (t >= 2 && lane < 4) {
                float* op = out + (size_t)(r0 + lane) * ostride + (size_t)(t - 2) * 3;
                op[0] = ao[0] + bl0; op[1] = ao[1] + bl1; op[2] = ao[2] + bl2;
            }
            if (t + 1 < TSEQ && lane < 12)
                Wt[xoff] = xpre[(t + 1) * 12 + xr * 3 + xj];
        }
        __syncthreads();
    }

    // ---- drain stage (t=TSEQ): B(T-1) + out(T-2). reads Sb[0], h2(T-1)->Sb[1] ----
    {
        _Float16* Rb = Sb[0];
        _Float16* Wt = Sb[1];
        f4 ao = {0.f, 0.f, 0.f, 0.f};
        if (mfmaw) {
            f4 b0 = {0.f,0.f,0.f,0.f}, b1 = b0;
            #pragma unroll
            for (int kt = 0; kt < 7; kt++) {
                h8 bf = (_Float16)0.f;
                if (col < 4) bf = *(const h8*)(Rb + kt * 512 + boff);
                MFMA(b0, A2[0][kt], bf); MFMA(b1, A2[1][kt], bf);
            }
            if (col < 4) {
                *(f4*)&zwB[w][tb + 0][col][4 * q] = b0;
                *(f4*)&zwB[w][tb + 1][col][4 * q] = b1;
            }
        } else if (wid == 7) {
            #pragma unroll
            for (int kk = 0; kk < 4; kk++) {
                h8 bf = (_Float16)0.f;
                if (col < 4) bf = *(const h8*)(Rb + (kk + 3) * 512 + boff);
                MFMA(ao, AO[kk], bf);
            }
        }
        __syncthreads();
        if (wid >= 8 && wid < 15) {
            int w2 = wid - 8;
            float z0 = zwB[w2][0][r_ew][ul], z1 = zwB[w2][1][r_ew][ul];
            float z2 = zwB[w2][2][r_ew][ul], z3 = zwB[w2][3][r_ew][ul];
            float ig = sigm(z0), fg = sigm(z1), gg = tanhf_(z2), og = sigm(z3);
            c2 = fg * c2 + ig * gg;
            float h2v = og * tanhf_(c2);
            if (ewv) Wt[slot2] = (_Float16)h2v;
        } else if (wid == 7 && lane < 4) {
            float* op = out + (size_t)(r0 + lane) * ostride + (size_t)(TSEQ - 2) * 3;
            op[0] = ao[0] + bl0; op[1] = ao[1] + bl1; op[2] = ao[2] + bl2;
        }
        __syncthreads();
    }

    // ---- future (autoregressive), serial 5-barrier steps ----
    for (int t = TSEQ; t < steps; ++t) {
        _Float16* R = Sb[t & 1];
        _Float16* W = Sb[1 - (t & 1)];
        // ph0: wave7 out(t-1) from W h2-region; store + feedback x(t) -> R
        if (wid == 7) {
            f4 ao = {0.f, 0.f, 0.f, 0.f};
            #pragma unroll
            for (int kk = 0; kk < 4; kk++) {
                h8 bf = (_Float16)0.f;
                if (col < 4) bf = *(const h8*)(W + (kk + 3) * 512 + boff);
                MFMA(ao, AO[kk], bf);
            }
            if (lane < 4) {
                float o0 = ao[0] + bl0, o1 = ao[1] + bl1, o2 = ao[2] + bl2;
                float* op = out + (size_t)(r0 + lane) * ostride + (size_t)(t - 1) * 3;
                op[0] = o0; op[1] = o1; op[2] = o2;
                R[12 * 128 + lane * 8 + 5] = (_Float16)o0;
                R[12 * 128 + lane * 8 + 6] = (_Float16)o1;
                R[12 * 128 + lane * 8 + 7] = (_Float16)o2;
            }
        }
        __syncthreads();
        // ph1: A(t) MFMA from R kt0..3 -> zwA
        if (mfmaw) {
            f4 a0 = {0.f,0.f,0.f,0.f}, a1 = a0;
            #pragma unroll
            for (int kt = 0; kt < 4; kt++) {
                h8 bf = (_Float16)0.f;
                if (col < 4) bf = *(const h8*)(R + kt * 512 + boff);
                MFMA(a0, A1[0][kt], bf); MFMA(a1, A1[1][kt], bf);
            }
            if (col < 4) {
                *(f4*)&zwA[w][tb + 0][col][4 * q] = a0;
                *(f4*)&zwA[w][tb + 1][col][4 * q] = a1;
            }
        }
        __syncthreads();
        // ph2: L1 ew -> h1(t) -> W
        if (wid < 7) {
            float z0 = zwA[wid][0][r_ew][ul], z1 = zwA[wid][1][r_ew][ul];
            float z2 = zwA[wid][2][r_ew][ul], z3 = zwA[wid][3][r_ew][ul];
            float ig = sigm(z0), fg = sigm(z1), gg = tanhf_(z2), og = sigm(z3);
            c1 = fg * c1 + ig * gg;
            float h1v = og * tanhf_(c1);
            if (ewv) W[slot1] = (_Float16)h1v;
        }
        __syncthreads();
        // ph3: B(t) MFMA from W kt0..6 (h1(t), h2(t-1)) -> zwB
        if (mfmaw) {
            f4 b0 = {0.f,0.f,0.f,0.f}, b1 = b0;
            #pragma unroll
            for (int kt = 0; kt < 7; kt++) {
                h8 bf = (_Float16)0.f;
                if (col < 4) bf = *(const h8*)(W + kt * 512 + boff);
                MFMA(b0, A2[0][kt], bf); MFMA(b1, A2[1][kt], bf);
            }
            if (col < 4) {
                *(f4*)&zwB[w][tb + 0][col][4 * q] = b0;
                *(f4*)&zwB[w][tb + 1][col][4 * q] = b1;
            }
        }
        __syncthreads();
        // ph4: L2 ew -> h2(t) -> R
        if (wid >= 8 && wid < 15) {
            int w2 = wid - 8;
            float z0 = zwB[w2][0][r_ew][ul], z1 = zwB[w2][1][r_ew][ul];
            float z2 = zwB[w2][2][r_ew][ul], z3 = zwB[w2][3][r_ew][ul];
            float ig = sigm(z0), fg = sigm(z1), gg = tanhf_(z2), og = sigm(z3);
            c2 = fg * c2 + ig * gg;
            float h2v = og * tanhf_(c2);
            if (ewv) R[slot2] = (_Float16)h2v;
        }
        __syncthreads();
    }

    // ---- epilogue: out(steps-1) from h2(steps-1) in Sb[1] ----
    if (wid == 7) {
        f4 ao = {0.f, 0.f, 0.f, 0.f};
        #pragma unroll
        for (int kk = 0; kk < 4; kk++) {
            h8 bf = (_Float16)0.f;
            if (col < 4) bf = *(const h8*)(&Sb[1][0] + (kk + 3) * 512 + boff);
            MFMA(ao, AO[kk], bf);
        }
        if (lane < 4) {
            float* op = out + (size_t)(r0 + lane) * ostride + (size_t)(steps - 1) * 3;
            op[0] = ao[0] + bl0; op[1] = ao[1] + bl1; op[2] = ao[2] + bl2;
        }
    }
}

extern "C" void kernel_launch(void* const* d_in, const int* in_sizes, int n_in,
                              void* d_out, int out_size, void* d_ws, size_t ws_size,
                              hipStream_t stream) {
    const float* input = (const float*)d_in[0];
    const float* W_ih1 = (const float*)d_in[1];
    const float* W_hh1 = (const float*)d_in[2];
    const float* b_ih1 = (const float*)d_in[3];
    const float* b_hh1 = (const float*)d_in[4];
    const float* W_ih2 = (const float*)d_in[5];
    const float* W_hh2 = (const float*)d_in[6];
    const float* b_ih2 = (const float*)d_in[7];
    const float* b_hh2 = (const float*)d_in[8];
    const float* Wl    = (const float*)d_in[9];
    const float* bl    = (const float*)d_in[10];
    int steps = out_size / (BATCH * 3);       // 288
    _Float16* wsA = (_Float16*)d_ws;

    hipLaunchKernelGGL(prep_kernel, dim3(512), dim3(256), 0, stream,
                       W_ih1, W_hh1, b_ih1, b_hh1, W_ih2, W_hh2, b_ih2, b_hh2, Wl, wsA);
    hipLaunchKernelGGL(lstm_kernel, dim3(NBLK), dim3(NTHR), 0, stream,
                       input, wsA, bl, steps, (float*)d_out);
}

// Round 16
// 521.763 us; speedup vs baseline: 1.0052x; 1.0052x over previous
//
#include <hip/hip_runtime.h>
#include <hip/hip_bf16.h>

#define HID 101
#define BATCH 1024
#define RPB 4
#define NBLK 256
#define NTHR 1024
#define TSEQ 256

#define A1SZ  (7*4*4*512)    // 57344 halfs
#define A2SZ  (7*4*7*512)    // 100352 halfs
#define A2OFF A1SZ
#define AOOFF (A1SZ + A2SZ)  // 157696
#define AOSZ  (4*512)

typedef _Float16 h8 __attribute__((ext_vector_type(8)));
typedef float f4 __attribute__((ext_vector_type(4)));

// ---------------------------------------------------------------------------
// Combined state vector (K=224, 7 k-tiles of 32):
//   k 0..100 : h1    k 101..103 : x    k 104 : one    k 112..212 : h2
// A1 (L1, kt0..3): k<101->W_hh1[g][k]; 101..103->W_ih1; 104->b1; else 0.
// A2 (L2, kt0..6): k<101->W_ih2[g][k]; 104->b2; 112..212->W_hh2[g][k-112]; else 0.
// AO (out head, frags for kt3..6): row j<3: k 112..212 -> Wl[j][k-112]; else 0.
// Fragment: lane l holds A[row=l&15][k = kt*32 + ((l>>4)&3)*8 + i], i=0..7.
// ---------------------------------------------------------------------------
__global__ void prep_kernel(const float* __restrict__ W_ih1, const float* __restrict__ W_hh1,
                            const float* __restrict__ b_ih1, const float* __restrict__ b_hh1,
                            const float* __restrict__ W_ih2, const float* __restrict__ W_hh2,
                            const float* __restrict__ b_ih2, const float* __restrict__ b_hh2,
                            const float* __restrict__ Wl, _Float16* __restrict__ wsA) {
    int idx = blockIdx.x * blockDim.x + threadIdx.x;
    int stride = gridDim.x * blockDim.x;
    for (int t = idx; t < A1SZ; t += stride) {
        int i = t & 7, lane = (t >> 3) & 63, kt = (t >> 9) & 3, tau = (t >> 11) & 3, w = t >> 13;
        int k = kt * 32 + ((lane >> 4) & 3) * 8 + i;
        int u = 16 * w + (lane & 15);
        float v = 0.f;
        if (u < HID) {
            int g = tau * HID + u;
            if (k < HID) v = W_hh1[g * HID + k];
            else if (k >= 101 && k <= 103) v = W_ih1[g * 3 + (k - 101)];
            else if (k == 104) v = b_ih1[g] + b_hh1[g];
        }
        wsA[t] = (_Float16)v;
    }
    for (int t = idx; t < A2SZ; t += stride) {
        int i = t & 7, lane = (t >> 3) & 63;
        int rem = t >> 9;
        int kt = rem % 7; rem /= 7;
        int tau = rem & 3, w = rem >> 2;
        int k = kt * 32 + ((lane >> 4) & 3) * 8 + i;
        int u = 16 * w + (lane & 15);
        float v = 0.f;
        if (u < HID) {
            int g = tau * HID + u;
            if (k < HID) v = W_ih2[g * HID + k];
            else if (k == 104) v = b_ih2[g] + b_hh2[g];
            else if (k >= 112 && k < 213) v = W_hh2[g * HID + (k - 112)];
        }
        wsA[A2OFF + t] = (_Float16)v;
    }
    for (int t = idx; t < AOSZ; t += stride) {
        int i = t & 7, lane = (t >> 3) & 63, kk = (t >> 9) & 3;
        int k = (kk + 3) * 32 + ((lane >> 4) & 3) * 8 + i;
        int j = lane & 15;
        float v = (j < 3 && k >= 112 && k < 213) ? Wl[j * HID + (k - 112)] : 0.f;
        wsA[AOOFF + t] = (_Float16)v;
    }
}

__device__ __forceinline__ float sigm(float z) {
    return __builtin_amdgcn_rcpf(1.f + __expf(-z));
}
__device__ __forceinline__ float tanhf_(float z) {
    return 1.f - 2.f * __builtin_amdgcn_rcpf(__expf(2.f * z) + 1.f);
}

#define MFMA(acc, a, b) acc = __builtin_amdgcn_mfma_f32_16x16x32_f16(a, b, acc, 0, 0, 0)

// ---------------------------------------------------------------------------
// persistent kernel: 256 blocks x 1024 thr (16 waves, 4 waves/SIMD).
// __launch_bounds__(1024, 4): min 4 waves/EU -> hard 128-VGPR cap, exactly
// the tau-split budget (88 weights + 16 acc + transients). Prevents the
// r15 failure where the allocator chose 64 regs and spilled weights.
// Tau-split: wave w (0..6) holds tau{0,1} of unit-group w; wave w+8 holds
// tau{2,3}. Teacher stage = 2 barriers; future = 5-barrier serial.
// ---------------------------------------------------------------------------
__global__ __launch_bounds__(NTHR, 4) void lstm_kernel(
    const float* __restrict__ input, const _Float16* __restrict__ wsA,
    const float* __restrict__ bl, int steps, float* __restrict__ out)
{
    const int tid = threadIdx.x;
    const int wid = tid >> 6, lane = tid & 63;
    const int q = lane >> 4, col = lane & 15;
    const int r0 = blockIdx.x * RPB;
    const int ostride = steps * 3;

    const int w = wid & 7;                       // unit-group (0..6 valid)
    const bool mfmaw = (w < 7) && (wid != 7);    // waves 0-6, 8-14
    const int tb = (wid < 8) ? 0 : 2;            // tau base for this wave

    __shared__ _Float16 Sb[2][3584];       // combined state buffers
    __shared__ float zwA[7][4][4][16];     // L1 z exchange [w][tau][row][unit]
    __shared__ float zwB[7][4][4][16];     // L2 z exchange
    __shared__ _Float16 xpre[TSEQ * 12];   // staged inputs (f16)

    // --- weights: volatile loads -> execute once, stay register-resident ---
    h8 A1[2][4];   // tau tb, tb+1
    h8 A2[2][7];
    h8 AO[4];      // wave 7 only: out head
    if (mfmaw) {
        #pragma unroll
        for (int tt = 0; tt < 2; tt++) {
            #pragma unroll
            for (int kt = 0; kt < 4; kt++)
                A1[tt][kt] = *(const volatile h8*)(
                    wsA + ((size_t)((w * 4 + tb + tt) * 4 + kt) * 512 + lane * 8));
            #pragma unroll
            for (int kt = 0; kt < 7; kt++)
                A2[tt][kt] = *(const volatile h8*)(
                    wsA + (size_t)A2OFF + ((size_t)((w * 4 + tb + tt) * 7 + kt) * 512 + lane * 8));
        }
    } else if (wid == 7) {
        #pragma unroll
        for (int kt = 0; kt < 4; kt++)
            AO[kt] = *(const volatile h8*)(
                wsA + (size_t)AOOFF + ((size_t)(kt) * 512 + lane * 8));
    }
    const float bl0 = bl[0], bl1 = bl[1], bl2 = bl[2];

    // lane geometry
    const int r_ew = lane & 3, ul = lane >> 2;
    const int uw = (wid < 8) ? wid : (wid - 8);          // ew unit-group
    const int u = 16 * uw + ul;
    const bool ewv = (uw < 7) && (u < HID);
    const int slot1 = (u >> 3) * 128 + r_ew * 8 + (u & 7);           // h1 (k=u)
    const int slot2 = (14 + (u >> 3)) * 128 + r_ew * 8 + (u & 7);    // h2 (k=112+u)
    const int boff = q * 128 + col * 8;
    const int xr = lane / 3, xj = lane - 3 * xr;                     // wave7 lanes<12
    const int xoff = 12 * 128 + xr * 8 + 5 + xj;                     // x slot (k=101+xj)

    // ---- prologue ----
    for (int i2 = tid; i2 < 3584; i2 += NTHR) {
        Sb[0][i2] = (_Float16)0.f; Sb[1][i2] = (_Float16)0.f;
    }
    for (int g = tid; g < RPB * TSEQ * 3; g += NTHR) {
        int r = g / (TSEQ * 3), rem = g - r * (TSEQ * 3);
        int tt = rem / 3, j = rem - 3 * tt;
        xpre[tt * 12 + r * 3 + j] = (_Float16)input[(size_t)(r0 + r) * (TSEQ * 3) + rem];
    }
    __syncthreads();
    if (tid < 16) {   // bias-one slot k=104, both buffers
        Sb[0][13 * 128 + tid * 8] = (_Float16)1.0f;
        Sb[1][13 * 128 + tid * 8] = (_Float16)1.0f;
    }
    if (tid < 12) {  // x(0) -> S[0]
        int r = tid / 3, j = tid - 3 * (tid / 3);
        Sb[0][12 * 128 + r * 8 + 5 + j] = xpre[r * 3 + j];
    }
    float c1 = 0.f, c2 = 0.f;   // c1 live in waves 0-6; c2 in waves 8-14
    __syncthreads();

    // ---- teacher-forced pipeline: 2 barriers per step ----
    for (int t = 0; t < TSEQ; ++t) {
        _Float16* Rb = Sb[t & 1];
        _Float16* Wt = Sb[1 - (t & 1)];
        f4 ao = {0.f, 0.f, 0.f, 0.f};
        // ---- phase 1: MFMAs ----
        if (mfmaw) {
            f4 a0 = {0.f,0.f,0.f,0.f}, a1 = a0, b0 = a0, b1 = a0;
            #pragma unroll
            for (int kt = 0; kt < 7; kt++) {
                h8 bf = (_Float16)0.f;
                if (col < 4) bf = *(const h8*)(Rb + kt * 512 + boff);
                if (kt < 4) { MFMA(a0, A1[0][kt], bf); MFMA(a1, A1[1][kt], bf); }
                if (t >= 1) { MFMA(b0, A2[0][kt], bf); MFMA(b1, A2[1][kt], bf); }
            }
            if (col < 4) {
                *(f4*)&zwA[w][tb + 0][col][4 * q] = a0;
                *(f4*)&zwA[w][tb + 1][col][4 * q] = a1;
                if (t >= 1) {
                    *(f4*)&zwB[w][tb + 0][col][4 * q] = b0;
                    *(f4*)&zwB[w][tb + 1][col][4 * q] = b1;
                }
            }
        } else if (wid == 7 && t >= 2) {
            #pragma unroll
            for (int kk = 0; kk < 4; kk++) {
                h8 bf = (_Float16)0.f;
                if (col < 4) bf = *(const h8*)(Rb + (kk + 3) * 512 + boff);
                MFMA(ao, AO[kk], bf);
            }
        }
        __syncthreads();
        // ---- phase 2: elementwise + stores ----
        if (wid < 7) {          // L1 ew
            float z0 = zwA[wid][0][r_ew][ul], z1 = zwA[wid][1][r_ew][ul];
            float z2 = zwA[wid][2][r_ew][ul], z3 = zwA[wid][3][r_ew][ul];
            float ig = sigm(z0), fg = sigm(z1), gg = tanhf_(z2), og = sigm(z3);
            c1 = fg * c1 + ig * gg;
            float h1v = og * tanhf_(c1);
            if (ewv) Wt[slot1] = (_Float16)h1v;
        } else if (wid >= 8 && wid < 15) {   // L2 ew
            if (t >= 1) {
                int w2 = wid - 8;
                float z0 = zwB[w2][0][r_ew][ul], z1 = zwB[w2][1][r_ew][ul];
                float z2 = zwB[w2][2][r_ew][ul], z3 = zwB[w2][3][r_ew][ul];
                float ig = sigm(z0), fg = sigm(z1), gg = tanhf_(z2), og = sigm(z3);
                c2 = fg * c2 + ig * gg;
                float h2v = og * tanhf_(c2);
                if (ewv) Wt[slot2] = (_Float16)h2v;
            }
        } else if (wid == 7) {
            if (t >= 2 && lane < 4) {
                float* op = out + (size_t)(r0 + lane) * ostride + (size_t)(t - 2) * 3;
                op[0] = ao[0] + bl0; op[1] = ao[1] + bl1; op[2] = ao[2] + bl2;
            }
            if (t + 1 < TSEQ && lane < 12)
                Wt[xoff] = xpre[(t + 1) * 12 + xr * 3 + xj];
        }
        __syncthreads();
    }

    // ---- drain stage (t=TSEQ): B(T-1) + out(T-2). reads Sb[0], h2(T-1)->Sb[1] ----
    {
        _Float16* Rb = Sb[0];
        _Float16* Wt = Sb[1];
        f4 ao = {0.f, 0.f, 0.f, 0.f};
        if (mfmaw) {
            f4 b0 = {0.f,0.f,0.f,0.f}, b1 = b0;
            #pragma unroll
            for (int kt = 0; kt < 7; kt++) {
                h8 bf = (_Float16)0.f;
                if (col < 4) bf = *(const h8*)(Rb + kt * 512 + boff);
                MFMA(b0, A2[0][kt], bf); MFMA(b1, A2[1][kt], bf);
            }
            if (col < 4) {
                *(f4*)&zwB[w][tb + 0][col][4 * q] = b0;
                *(f4*)&zwB[w][tb + 1][col][4 * q] = b1;
            }
        } else if (wid == 7) {
            #pragma unroll
            for (int kk = 0; kk < 4; kk++) {
                h8 bf = (_Float16)0.f;
                if (col < 4) bf = *(const h8*)(Rb + (kk + 3) * 512 + boff);
                MFMA(ao, AO[kk], bf);
            }
        }
        __syncthreads();
        if (wid >= 8 && wid < 15) {
            int w2 = wid - 8;
            float z0 = zwB[w2][0][r_ew][ul], z1 = zwB[w2][1][r_ew][ul];
            float z2 = zwB[w2][2][r_ew][ul], z3 = zwB[w2][3][r_ew][ul];
            float ig = sigm(z0), fg = sigm(z1), gg = tanhf_(z2), og = sigm(z3);
            c2 = fg * c2 + ig * gg;
            float h2v = og * tanhf_(c2);
            if (ewv) Wt[slot2] = (_Float16)h2v;
        } else if (wid == 7 && lane < 4) {
            float* op = out + (size_t)(r0 + lane) * ostride + (size_t)(TSEQ - 2) * 3;
            op[0] = ao[0] + bl0; op[1] = ao[1] + bl1; op[2] = ao[2] + bl2;
        }
        __syncthreads();
    }

    // ---- future (autoregressive), serial 5-barrier steps ----
    for (int t = TSEQ; t < steps; ++t) {
        _Float16* R = Sb[t & 1];
        _Float16* W = Sb[1 - (t & 1)];
        // ph0: wave7 out(t-1) from W h2-region; store + feedback x(t) -> R
        if (wid == 7) {
            f4 ao = {0.f, 0.f, 0.f, 0.f};
            #pragma unroll
            for (int kk = 0; kk < 4; kk++) {
                h8 bf = (_Float16)0.f;
                if (col < 4) bf = *(const h8*)(W + (kk + 3) * 512 + boff);
                MFMA(ao, AO[kk], bf);
            }
            if (lane < 4) {
                float o0 = ao[0] + bl0, o1 = ao[1] + bl1, o2 = ao[2] + bl2;
                float* op = out + (size_t)(r0 + lane) * ostride + (size_t)(t - 1) * 3;
                op[0] = o0; op[1] = o1; op[2] = o2;
                R[12 * 128 + lane * 8 + 5] = (_Float16)o0;
                R[12 * 128 + lane * 8 + 6] = (_Float16)o1;
                R[12 * 128 + lane * 8 + 7] = (_Float16)o2;
            }
        }
        __syncthreads();
        // ph1: A(t) MFMA from R kt0..3 -> zwA
        if (mfmaw) {
            f4 a0 = {0.f,0.f,0.f,0.f}, a1 = a0;
            #pragma unroll
            for (int kt = 0; kt < 4; kt++) {
                h8 bf = (_Float16)0.f;
                if (col < 4) bf = *(const h8*)(R + kt * 512 + boff);
                MFMA(a0, A1[0][kt], bf); MFMA(a1, A1[1][kt], bf);
            }
            if (col < 4) {
                *(f4*)&zwA[w][tb + 0][col][4 * q] = a0;
                *(f4*)&zwA[w][tb + 1][col][4 * q] = a1;
            }
        }
        __syncthreads();
        // ph2: L1 ew -> h1(t) -> W
        if (wid < 7) {
            float z0 = zwA[wid][0][r_ew][ul], z1 = zwA[wid][1][r_ew][ul];
            float z2 = zwA[wid][2][r_ew][ul], z3 = zwA[wid][3][r_ew][ul];
            float ig = sigm(z0), fg = sigm(z1), gg = tanhf_(z2), og = sigm(z3);
            c1 = fg * c1 + ig * gg;
            float h1v = og * tanhf_(c1);
            if (ewv) W[slot1] = (_Float16)h1v;
        }
        __syncthreads();
        // ph3: B(t) MFMA from W kt0..6 (h1(t), h2(t-1)) -> zwB
        if (mfmaw) {
            f4 b0 = {0.f,0.f,0.f,0.f}, b1 = b0;
            #pragma unroll
            for (int kt = 0; kt < 7; kt++) {
                h8 bf = (_Float16)0.f;
                if (col < 4) bf = *(const h8*)(W + kt * 512 + boff);
                MFMA(b0, A2[0][kt], bf); MFMA(b1, A2[1][kt], bf);
            }
            if (col < 4) {
                *(f4*)&zwB[w][tb + 0][col][4 * q] = b0;
                *(f4*)&zwB[w][tb + 1][col][4 * q] = b1;
            }
        }
        __syncthreads();
        // ph4: L2 ew -> h2(t) -> R
        if (wid >= 8 && wid < 15) {
            int w2 = wid - 8;
            float z0 = zwB[w2][0][r_ew][ul], z1 = zwB[w2][1][r_ew][ul];
            float z2 = zwB[w2][2][r_ew][ul], z3 = zwB[w2][3][r_ew][ul];
            float ig = sigm(z0), fg = sigm(z1), gg = tanhf_(z2), og = sigm(z3);
            c2 = fg * c2 + ig * gg;
            float h2v = og * tanhf_(c2);
            if (ewv) R[slot2] = (_Float16)h2v;
        }
        __syncthreads();
    }

    // ---- epilogue: out(steps-1) from h2(steps-1) in Sb[1] ----
    if (wid == 7) {
        f4 ao = {0.f, 0.f, 0.f, 0.f};
        #pragma unroll
        for (int kk = 0; kk < 4; kk++) {
            h8 bf = (_Float16)0.f;
            if (col < 4) bf = *(const h8*)(&Sb[1][0] + (kk + 3) * 512 + boff);
            MFMA(ao, AO[kk], bf);
        }
        if (lane < 4) {
            float* op = out + (size_t)(r0 + lane) * ostride + (size_t)(steps - 1) * 3;
            op[0] = ao[0] + bl0; op[1] = ao[1] + bl1; op[2] = ao[2] + bl2;
        }
    }
}

extern "C" void kernel_launch(void* const* d_in, const int* in_sizes, int n_in,
                              void* d_out, int out_size, void* d_ws, size_t ws_size,
                              hipStream_t stream) {
    const float* input = (const float*)d_in[0];
    const float* W_ih1 = (const float*)d_in[1];
    const float* W_hh1 = (const float*)d_in[2];
    const float* b_ih1 = (const float*)d_in[3];
    const float* b_hh1 = (const float*)d_in[4];
    const float* W_ih2 = (const float*)d_in[5];
    const float* W_hh2 = (const float*)d_in[6];
    const float* b_ih2 = (const float*)d_in[7];
    const float* b_hh2 = (const float*)d_in[8];
    const float* Wl    = (const float*)d_in[9];
    const float* bl    = (const float*)d_in[10];
    int steps = out_size / (BATCH * 3);       // 288
    _Float16* wsA = (_Float16*)d_ws;

    hipLaunchKernelGGL(prep_kernel, dim3(512), dim3(256), 0, stream,
                       W_ih1, W_hh1, b_ih1, b_hh1, W_ih2, W_hh2, b_ih2, b_hh2, Wl, wsA);
    hipLaunchKernelGGL(lstm_kernel, dim3(NBLK), dim3(NTHR), 0, stream,
                       input, wsA, bl, steps, (float*)d_out);
}

// Round 17
// 481.978 us; speedup vs baseline: 1.0881x; 1.0825x over previous
//
#include <hip/hip_runtime.h>
#include <hip/hip_bf16.h>

#define HID 101
#define BATCH 1024
#define RPB 4
#define NBLK 256
#define NTHR 1024
#define TSEQ 256

#define A1SZ  (7*4*4*512)    // 57344 halfs
#define A2SZ  (7*4*7*512)    // 100352 halfs
#define A2OFF A1SZ
#define AOOFF (A1SZ + A2SZ)  // 157696
#define AOSZ  (4*512)

typedef _Float16 h8 __attribute__((ext_vector_type(8)));
typedef float f4 __attribute__((ext_vector_type(4)));

// ---------------------------------------------------------------------------
// Combined state vector (K=224, 7 k-tiles of 32):
//   k 0..100 : h1    k 101..103 : x    k 104 : one    k 112..212 : h2
// A1 (L1, kt0..3): k<101->W_hh1[g][k]; 101..103->W_ih1; 104->b1; else 0.
// A2 (L2, kt0..6): k<101->W_ih2[g][k]; 104->b2; 112..212->W_hh2[g][k-112]; else 0.
// AO (out head, frags for kt3..6): row j<3: k 112..212 -> Wl[j][k-112]; else 0.
// Fragment: lane l holds A[row=l&15][k = kt*32 + ((l>>4)&3)*8 + i], i=0..7.
// ---------------------------------------------------------------------------
__global__ void prep_kernel(const float* __restrict__ W_ih1, const float* __restrict__ W_hh1,
                            const float* __restrict__ b_ih1, const float* __restrict__ b_hh1,
                            const float* __restrict__ W_ih2, const float* __restrict__ W_hh2,
                            const float* __restrict__ b_ih2, const float* __restrict__ b_hh2,
                            const float* __restrict__ Wl, _Float16* __restrict__ wsA) {
    int idx = blockIdx.x * blockDim.x + threadIdx.x;
    int stride = gridDim.x * blockDim.x;
    for (int t = idx; t < A1SZ; t += stride) {
        int i = t & 7, lane = (t >> 3) & 63, kt = (t >> 9) & 3, tau = (t >> 11) & 3, w = t >> 13;
        int k = kt * 32 + ((lane >> 4) & 3) * 8 + i;
        int u = 16 * w + (lane & 15);
        float v = 0.f;
        if (u < HID) {
            int g = tau * HID + u;
            if (k < HID) v = W_hh1[g * HID + k];
            else if (k >= 101 && k <= 103) v = W_ih1[g * 3 + (k - 101)];
            else if (k == 104) v = b_ih1[g] + b_hh1[g];
        }
        wsA[t] = (_Float16)v;
    }
    for (int t = idx; t < A2SZ; t += stride) {
        int i = t & 7, lane = (t >> 3) & 63;
        int rem = t >> 9;
        int kt = rem % 7; rem /= 7;
        int tau = rem & 3, w = rem >> 2;
        int k = kt * 32 + ((lane >> 4) & 3) * 8 + i;
        int u = 16 * w + (lane & 15);
        float v = 0.f;
        if (u < HID) {
            int g = tau * HID + u;
            if (k < HID) v = W_ih2[g * HID + k];
            else if (k == 104) v = b_ih2[g] + b_hh2[g];
            else if (k >= 112 && k < 213) v = W_hh2[g * HID + (k - 112)];
        }
        wsA[A2OFF + t] = (_Float16)v;
    }
    for (int t = idx; t < AOSZ; t += stride) {
        int i = t & 7, lane = (t >> 3) & 63, kk = (t >> 9) & 3;
        int k = (kk + 3) * 32 + ((lane >> 4) & 3) * 8 + i;
        int j = lane & 15;
        float v = (j < 3 && k >= 112 && k < 213) ? Wl[j * HID + (k - 112)] : 0.f;
        wsA[AOOFF + t] = (_Float16)v;
    }
}

__device__ __forceinline__ float sigm(float z) {
    return __builtin_amdgcn_rcpf(1.f + __expf(-z));
}
__device__ __forceinline__ float tanhf_(float z) {
    return 1.f - 2.f * __builtin_amdgcn_rcpf(__expf(2.f * z) + 1.f);
}

#define MFMA(acc, a, b) acc = __builtin_amdgcn_mfma_f32_16x16x32_f16(a, b, acc, 0, 0, 0)

// ---------------------------------------------------------------------------
// persistent kernel: 256 blocks x 1024 thr (16 waves, 4 waves/SIMD).
// amdgpu_waves_per_eu(4,4): min AND max 4 waves/EU -> allocator has no
// incentive to squeeze below 128 VGPRs, so the 88-reg weight set stays
// register-resident (r15/r16 failed because min-only bounds let the
// allocator target 8 waves/EU at 64 regs and spill the weights).
// Tau-split: wave w (0..6) holds tau{0,1} of unit-group w; wave w+8 holds
// tau{2,3}; wave 7 out-head frags live in A1[0][0..3] (no extra array).
// Teacher stage = 2 barriers; future = 5-barrier serial.
// ---------------------------------------------------------------------------
__global__ __launch_bounds__(NTHR)
__attribute__((amdgpu_waves_per_eu(4, 4)))
void lstm_kernel(
    const float* __restrict__ input, const _Float16* __restrict__ wsA,
    const float* __restrict__ bl, int steps, float* __restrict__ out)
{
    const int tid = threadIdx.x;
    const int wid = tid >> 6, lane = tid & 63;
    const int q = lane >> 4, col = lane & 15;
    const int r0 = blockIdx.x * RPB;
    const int ostride = steps * 3;

    const int w = wid & 7;                       // unit-group (0..6 valid)
    const bool mfmaw = (w < 7) && (wid != 7);    // waves 0-6, 8-14
    const int tb = (wid < 8) ? 0 : 2;            // tau base for this wave

    __shared__ _Float16 Sb[2][3584];       // combined state buffers
    __shared__ float zwA[7][4][4][16];     // L1 z exchange [w][tau][row][unit]
    __shared__ float zwB[7][4][4][16];     // L2 z exchange
    __shared__ _Float16 xpre[TSEQ * 12];   // staged inputs (f16)

    // --- weights: volatile loads -> execute once, stay register-resident ---
    h8 A1[2][4];   // mfma waves: tau tb,tb+1 of L1. wave7: A1[0][0..3] = out head.
    h8 A2[2][7];   // mfma waves: tau tb,tb+1 of L2.
    if (mfmaw) {
        #pragma unroll
        for (int tt = 0; tt < 2; tt++) {
            #pragma unroll
            for (int kt = 0; kt < 4; kt++)
                A1[tt][kt] = *(const volatile h8*)(
                    wsA + ((size_t)((w * 4 + tb + tt) * 4 + kt) * 512 + lane * 8));
            #pragma unroll
            for (int kt = 0; kt < 7; kt++)
                A2[tt][kt] = *(const volatile h8*)(
                    wsA + (size_t)A2OFF + ((size_t)((w * 4 + tb + tt) * 7 + kt) * 512 + lane * 8));
        }
    } else if (wid == 7) {
        #pragma unroll
        for (int kt = 0; kt < 4; kt++)
            A1[0][kt] = *(const volatile h8*)(
                wsA + (size_t)AOOFF + ((size_t)(kt) * 512 + lane * 8));
    }
    const float bl0 = bl[0], bl1 = bl[1], bl2 = bl[2];

    // lane geometry
    const int r_ew = lane & 3, ul = lane >> 2;
    const int uw = (wid < 8) ? wid : (wid - 8);          // ew unit-group
    const int u = 16 * uw + ul;
    const bool ewv = (uw < 7) && (u < HID);
    const int slot1 = (u >> 3) * 128 + r_ew * 8 + (u & 7);           // h1 (k=u)
    const int slot2 = (14 + (u >> 3)) * 128 + r_ew * 8 + (u & 7);    // h2 (k=112+u)
    const int boff = q * 128 + col * 8;
    const int xr = lane / 3, xj = lane - 3 * xr;                     // wave7 lanes<12
    const int xoff = 12 * 128 + xr * 8 + 5 + xj;                     // x slot (k=101+xj)

    // ---- prologue ----
    for (int i2 = tid; i2 < 3584; i2 += NTHR) {
        Sb[0][i2] = (_Float16)0.f; Sb[1][i2] = (_Float16)0.f;
    }
    for (int g = tid; g < RPB * TSEQ * 3; g += NTHR) {
        int r = g / (TSEQ * 3), rem = g - r * (TSEQ * 3);
        int tt = rem / 3, j = rem - 3 * tt;
        xpre[tt * 12 + r * 3 + j] = (_Float16)input[(size_t)(r0 + r) * (TSEQ * 3) + rem];
    }
    __syncthreads();
    if (tid < 16) {   // bias-one slot k=104, both buffers
        Sb[0][13 * 128 + tid * 8] = (_Float16)1.0f;
        Sb[1][13 * 128 + tid * 8] = (_Float16)1.0f;
    }
    if (tid < 12) {  // x(0) -> S[0]
        int r = tid / 3, j = tid - 3 * (tid / 3);
        Sb[0][12 * 128 + r * 8 + 5 + j] = xpre[r * 3 + j];
    }
    float c1 = 0.f, c2 = 0.f;   // c1 live in waves 0-6; c2 in waves 8-14
    __syncthreads();

    // ---- teacher-forced pipeline: 2 barriers per step ----
    for (int t = 0; t < TSEQ; ++t) {
        _Float16* Rb = Sb[t & 1];
        _Float16* Wt = Sb[1 - (t & 1)];
        f4 ao = {0.f, 0.f, 0.f, 0.f};
        // ---- phase 1: MFMAs ----
        if (mfmaw) {
            f4 a0 = {0.f,0.f,0.f,0.f}, a1 = a0, b0 = a0, b1 = a0;
            #pragma unroll
            for (int kt = 0; kt < 7; kt++) {
                h8 bf = (_Float16)0.f;
                if (col < 4) bf = *(const h8*)(Rb + kt * 512 + boff);
                if (kt < 4) { MFMA(a0, A1[0][kt], bf); MFMA(a1, A1[1][kt], bf); }
                if (t >= 1) { MFMA(b0, A2[0][kt], bf); MFMA(b1, A2[1][kt], bf); }
            }
            if (col < 4) {
                *(f4*)&zwA[w][tb + 0][col][4 * q] = a0;
                *(f4*)&zwA[w][tb + 1][col][4 * q] = a1;
                if (t >= 1) {
                    *(f4*)&zwB[w][tb + 0][col][4 * q] = b0;
                    *(f4*)&zwB[w][tb + 1][col][4 * q] = b1;
                }
            }
        } else if (wid == 7 && t >= 2) {
            #pragma unroll
            for (int kk = 0; kk < 4; kk++) {
                h8 bf = (_Float16)0.f;
                if (col < 4) bf = *(const h8*)(Rb + (kk + 3) * 512 + boff);
                MFMA(ao, A1[0][kk], bf);
            }
        }
        __syncthreads();
        // ---- phase 2: elementwise + stores ----
        if (wid < 7) {          // L1 ew
            float z0 = zwA[wid][0][r_ew][ul], z1 = zwA[wid][1][r_ew][ul];
            float z2 = zwA[wid][2][r_ew][ul], z3 = zwA[wid][3][r_ew][ul];
            float ig = sigm(z0), fg = sigm(z1), gg = tanhf_(z2), og = sigm(z3);
            c1 = fg * c1 + ig * gg;
            float h1v = og * tanhf_(c1);
            if (ewv) Wt[slot1] = (_Float16)h1v;
        } else if (wid >= 8 && wid < 15) {   // L2 ew
            if (t >= 1) {
                int w2 = wid - 8;
                float z0 = zwB[w2][0][r_ew][ul], z1 = zwB[w2][1][r_ew][ul];
                float z2 = zwB[w2][2][r_ew][ul], z3 = zwB[w2][3][r_ew][ul];
                float ig = sigm(z0), fg = sigm(z1), gg = tanhf_(z2), og = sigm(z3);
                c2 = fg * c2 + ig * gg;
                float h2v = og * tanhf_(c2);
                if (ewv) Wt[slot2] = (_Float16)h2v;
            }
        } else if (wid == 7) {
            if (t >= 2 && lane < 4) {
                float* op = out + (size_t)(r0 + lane) * ostride + (size_t)(t - 2) * 3;
                op[0] = ao[0] + bl0; op[1] = ao[1] + bl1; op[2] = ao[2] + bl2;
            }
            if (t + 1 < TSEQ && lane < 12)
                Wt[xoff] = xpre[(t + 1) * 12 + xr * 3 + xj];
        }
        __syncthreads();
    }

    // ---- drain stage (t=TSEQ): B(T-1) + out(T-2). reads Sb[0], h2(T-1)->Sb[1] ----
    {
        _Float16* Rb = Sb[0];
        _Float16* Wt = Sb[1];
        f4 ao = {0.f, 0.f, 0.f, 0.f};
        if (mfmaw) {
            f4 b0 = {0.f,0.f,0.f,0.f}, b1 = b0;
            #pragma unroll
            for (int kt = 0; kt < 7; kt++) {
                h8 bf = (_Float16)0.f;
                if (col < 4) bf = *(const h8*)(Rb + kt * 512 + boff);
                MFMA(b0, A2[0][kt], bf); MFMA(b1, A2[1][kt], bf);
            }
            if (col < 4) {
                *(f4*)&zwB[w][tb + 0][col][4 * q] = b0;
                *(f4*)&zwB[w][tb + 1][col][4 * q] = b1;
            }
        } else if (wid == 7) {
            #pragma unroll
            for (int kk = 0; kk < 4; kk++) {
                h8 bf = (_Float16)0.f;
                if (col < 4) bf = *(const h8*)(Rb + (kk + 3) * 512 + boff);
                MFMA(ao, A1[0][kk], bf);
            }
        }
        __syncthreads();
        if (wid >= 8 && wid < 15) {
            int w2 = wid - 8;
            float z0 = zwB[w2][0][r_ew][ul], z1 = zwB[w2][1][r_ew][ul];
            float z2 = zwB[w2][2][r_ew][ul], z3 = zwB[w2][3][r_ew][ul];
            float ig = sigm(z0), fg = sigm(z1), gg = tanhf_(z2), og = sigm(z3);
            c2 = fg * c2 + ig * gg;
            float h2v = og * tanhf_(c2);
            if (ewv) Wt[slot2] = (_Float16)h2v;
        } else if (wid == 7 && lane < 4) {
            float* op = out + (size_t)(r0 + lane) * ostride + (size_t)(TSEQ - 2) * 3;
            op[0] = ao[0] + bl0; op[1] = ao[1] + bl1; op[2] = ao[2] + bl2;
        }
        __syncthreads();
    }

    // ---- future (autoregressive), serial 5-barrier steps ----
    for (int t = TSEQ; t < steps; ++t) {
        _Float16* R = Sb[t & 1];
        _Float16* W = Sb[1 - (t & 1)];
        // ph0: wave7 out(t-1) from W h2-region; store + feedback x(t) -> R
        if (wid == 7) {
            f4 ao = {0.f, 0.f, 0.f, 0.f};
            #pragma unroll
            for (int kk = 0; kk < 4; kk++) {
                h8 bf = (_Float16)0.f;
                if (col < 4) bf = *(const h8*)(W + (kk + 3) * 512 + boff);
                MFMA(ao, A1[0][kk], bf);
            }
            if (lane < 4) {
                float o0 = ao[0] + bl0, o1 = ao[1] + bl1, o2 = ao[2] + bl2;
                float* op = out + (size_t)(r0 + lane) * ostride + (size_t)(t - 1) * 3;
                op[0] = o0; op[1] = o1; op[2] = o2;
                R[12 * 128 + lane * 8 + 5] = (_Float16)o0;
                R[12 * 128 + lane * 8 + 6] = (_Float16)o1;
                R[12 * 128 + lane * 8 + 7] = (_Float16)o2;
            }
        }
        __syncthreads();
        // ph1: A(t) MFMA from R kt0..3 -> zwA
        if (mfmaw) {
            f4 a0 = {0.f,0.f,0.f,0.f}, a1 = a0;
            #pragma unroll
            for (int kt = 0; kt < 4; kt++) {
                h8 bf = (_Float16)0.f;
                if (col < 4) bf = *(const h8*)(R + kt * 512 + boff);
                MFMA(a0, A1[0][kt], bf); MFMA(a1, A1[1][kt], bf);
            }
            if (col < 4) {
                *(f4*)&zwA[w][tb + 0][col][4 * q] = a0;
                *(f4*)&zwA[w][tb + 1][col][4 * q] = a1;
            }
        }
        __syncthreads();
        // ph2: L1 ew -> h1(t) -> W
        if (wid < 7) {
            float z0 = zwA[wid][0][r_ew][ul], z1 = zwA[wid][1][r_ew][ul];
            float z2 = zwA[wid][2][r_ew][ul], z3 = zwA[wid][3][r_ew][ul];
            float ig = sigm(z0), fg = sigm(z1), gg = tanhf_(z2), og = sigm(z3);
            c1 = fg * c1 + ig * gg;
            float h1v = og * tanhf_(c1);
            if (ewv) W[slot1] = (_Float16)h1v;
        }
        __syncthreads();
        // ph3: B(t) MFMA from W kt0..6 (h1(t), h2(t-1)) -> zwB
        if (mfmaw) {
            f4 b0 = {0.f,0.f,0.f,0.f}, b1 = b0;
            #pragma unroll
            for (int kt = 0; kt < 7; kt++) {
                h8 bf = (_Float16)0.f;
                if (col < 4) bf = *(const h8*)(W + kt * 512 + boff);
                MFMA(b0, A2[0][kt], bf); MFMA(b1, A2[1][kt], bf);
            }
            if (col < 4) {
                *(f4*)&zwB[w][tb + 0][col][4 * q] = b0;
                *(f4*)&zwB[w][tb + 1][col][4 * q] = b1;
            }
        }
        __syncthreads();
        // ph4: L2 ew -> h2(t) -> R
        if (wid >= 8 && wid < 15) {
            int w2 = wid - 8;
            float z0 = zwB[w2][0][r_ew][ul], z1 = zwB[w2][1][r_ew][ul];
            float z2 = zwB[w2][2][r_ew][ul], z3 = zwB[w2][3][r_ew][ul];
            float ig = sigm(z0), fg = sigm(z1), gg = tanhf_(z2), og = sigm(z3);
            c2 = fg * c2 + ig * gg;
            float h2v = og * tanhf_(c2);
            if (ewv) R[slot2] = (_Float16)h2v;
        }
        __syncthreads();
    }

    // ---- epilogue: out(steps-1) from h2(steps-1) in Sb[1] ----
    if (wid == 7) {
        f4 ao = {0.f, 0.f, 0.f, 0.f};
        #pragma unroll
        for (int kk = 0; kk < 4; kk++) {
            h8 bf = (_Float16)0.f;
            if (col < 4) bf = *(const h8*)(&Sb[1][0] + (kk + 3) * 512 + boff);
            MFMA(ao, A1[0][kk], bf);
        }
        if (lane < 4) {
            float* op = out + (size_t)(r0 + lane) * ostride + (size_t)(steps - 1) * 3;
            op[0] = ao[0] + bl0; op[1] = ao[1] + bl1; op[2] = ao[2] + bl2;
        }
    }
}

extern "C" void kernel_launch(void* const* d_in, const int* in_sizes, int n_in,
                              void* d_out, int out_size, void* d_ws, size_t ws_size,
                              hipStream_t stream) {
    const float* input = (const float*)d_in[0];
    const float* W_ih1 = (const float*)d_in[1];
    const float* W_hh1 = (const float*)d_in[2];
    const float* b_ih1 = (const float*)d_in[3];
    const float* b_hh1 = (const float*)d_in[4];
    const float* W_ih2 = (const float*)d_in[5];
    const float* W_hh2 = (const float*)d_in[6];
    const float* b_ih2 = (const float*)d_in[7];
    const float* b_hh2 = (const float*)d_in[8];
    const float* Wl    = (const float*)d_in[9];
    const float* bl    = (const float*)d_in[10];
    int steps = out_size / (BATCH * 3);       // 288
    _Float16* wsA = (_Float16*)d_ws;

    hipLaunchKernelGGL(prep_kernel, dim3(512), dim3(256), 0, stream,
                       W_ih1, W_hh1, b_ih1, b_hh1, W_ih2, W_hh2, b_ih2, b_hh2, Wl, wsA);
    hipLaunchKernelGGL(lstm_kernel, dim3(NBLK), dim3(NTHR), 0, stream,
                       input, wsA, bl, steps, (float*)d_out);
}